// Round 1
// baseline (860.844 us; speedup 1.0000x reference)
//
#include <hip/hip_runtime.h>
#include <math.h>

#define BATCH 8
#define CH    512
#define SEQ   2048
#define CKDIM 64

// ---------------------------------------------------------------------------
// Generic fp32 tiled GEMM for the 1x1-conv projections:
//   out[(b*M + r)*SEQ + l] = bias[r] + sum_c W[r*CH + c] * x[(b*CH + c)*SEQ + l]
// Tile: 64(rows r) x 64(cols l), BK=16, 256 threads, 4x4 micro-tile.
// ---------------------------------------------------------------------------
__global__ __launch_bounds__(256) void proj_kernel(
    const float* __restrict__ W, const float* __restrict__ bias,
    const float* __restrict__ x, float* __restrict__ out, int M)
{
    __shared__ float As[16][68];  // [k][m]  (m = r within tile)
    __shared__ float Bs[16][68];  // [k][n]  (n = l within tile)

    const int tid = threadIdx.x;
    const int b  = blockIdx.z;
    const int l0 = blockIdx.x * 64;
    const int r0 = blockIdx.y * 64;
    const int tx = tid & 15;
    const int ty = tid >> 4;

    const float* xb = x + (size_t)b * CH * SEQ + l0;

    float acc[4][4] = {};

    for (int k0 = 0; k0 < CH; k0 += 16) {
        // A tile: W[r0+m][k0+k] -> As[k][m]
        {
            const int k = tid & 15;
            const int m = tid >> 4;  // 0..15
            #pragma unroll
            for (int q = 0; q < 4; ++q)
                As[k][m + q * 16] = W[(size_t)(r0 + m + q * 16) * CH + k0 + k];
        }
        // B tile: x[b][k0+k][l0+n] -> Bs[k][n]
        {
            const int n = tid & 63;
            const int k = tid >> 6;  // 0..3
            #pragma unroll
            for (int q = 0; q < 4; ++q)
                Bs[k + q * 4][n] = xb[(size_t)(k0 + k + q * 4) * SEQ + n];
        }
        __syncthreads();
        #pragma unroll
        for (int kk = 0; kk < 16; ++kk) {
            float4 a  = *(const float4*)&As[kk][ty * 4];
            float4 bv = *(const float4*)&Bs[kk][tx * 4];
            float av[4] = {a.x, a.y, a.z, a.w};
            float bw[4] = {bv.x, bv.y, bv.z, bv.w};
            #pragma unroll
            for (int i2 = 0; i2 < 4; ++i2)
                #pragma unroll
                for (int j2 = 0; j2 < 4; ++j2)
                    acc[i2][j2] = fmaf(av[i2], bw[j2], acc[i2][j2]);
        }
        __syncthreads();
    }

    #pragma unroll
    for (int mm = 0; mm < 4; ++mm) {
        const int r = r0 + ty * 4 + mm;
        const float bb = bias[r];
        float4 v;
        v.x = acc[mm][0] + bb;
        v.y = acc[mm][1] + bb;
        v.z = acc[mm][2] + bb;
        v.w = acc[mm][3] + bb;
        *(float4*)&out[((size_t)b * M + r) * SEQ + l0 + tx * 4] = v;
    }
}

// ---------------------------------------------------------------------------
// Scores: att[i][j] = sum_k f[b][k][i] * g[b][k][j]   (K = 64)
// f,g are (B, CK, SEQ) row-major -> both tiles load directly as [k][m/n].
// ---------------------------------------------------------------------------
__global__ __launch_bounds__(256) void scores_kernel(
    const float* __restrict__ f, const float* __restrict__ g,
    float* __restrict__ att, int b0, long long attStride)
{
    __shared__ float As[16][68];  // [k][i]
    __shared__ float Bs[16][68];  // [k][j]

    const int tid = threadIdx.x;
    const int b = b0 + blockIdx.z;
    float* attb = att + (size_t)blockIdx.z * attStride;
    const int j0 = blockIdx.x * 64;
    const int i0 = blockIdx.y * 64;
    const int tx = tid & 15;
    const int ty = tid >> 4;

    const float* fb = f + (size_t)b * CKDIM * SEQ + i0;
    const float* gb = g + (size_t)b * CKDIM * SEQ + j0;

    float acc[4][4] = {};

    for (int k0 = 0; k0 < CKDIM; k0 += 16) {
        const int n = tid & 63;
        const int k = tid >> 6;  // 0..3
        #pragma unroll
        for (int q = 0; q < 4; ++q) {
            As[k + q * 4][n] = fb[(size_t)(k0 + k + q * 4) * SEQ + n];
            Bs[k + q * 4][n] = gb[(size_t)(k0 + k + q * 4) * SEQ + n];
        }
        __syncthreads();
        #pragma unroll
        for (int kk = 0; kk < 16; ++kk) {
            float4 a  = *(const float4*)&As[kk][ty * 4];
            float4 bv = *(const float4*)&Bs[kk][tx * 4];
            float av[4] = {a.x, a.y, a.z, a.w};
            float bw[4] = {bv.x, bv.y, bv.z, bv.w};
            #pragma unroll
            for (int i2 = 0; i2 < 4; ++i2)
                #pragma unroll
                for (int j2 = 0; j2 < 4; ++j2)
                    acc[i2][j2] = fmaf(av[i2], bw[j2], acc[i2][j2]);
        }
        __syncthreads();
    }

    #pragma unroll
    for (int mm = 0; mm < 4; ++mm) {
        float4 v;
        v.x = acc[mm][0]; v.y = acc[mm][1]; v.z = acc[mm][2]; v.w = acc[mm][3];
        *(float4*)&attb[(size_t)(i0 + ty * 4 + mm) * SEQ + j0 + tx * 4] = v;
    }
}

// ---------------------------------------------------------------------------
// Row softmax over j (in place). One block (256 thr) per row; 8 elems/thread.
// ---------------------------------------------------------------------------
__global__ __launch_bounds__(256) void softmax_kernel(
    float* __restrict__ att, long long attStride)
{
    float* row = att + (size_t)blockIdx.z * attStride + (size_t)blockIdx.x * SEQ;
    const int tid  = threadIdx.x;
    const int lane = tid & 63;
    const int wid  = tid >> 6;
    __shared__ float red[4];

    float v[8];
    float mx = -INFINITY;
    #pragma unroll
    for (int q = 0; q < 8; ++q) {
        v[q] = row[tid + q * 256];
        mx = fmaxf(mx, v[q]);
    }
    #pragma unroll
    for (int off = 32; off > 0; off >>= 1)
        mx = fmaxf(mx, __shfl_down(mx, off));
    if (lane == 0) red[wid] = mx;
    __syncthreads();
    const float m = fmaxf(fmaxf(red[0], red[1]), fmaxf(red[2], red[3]));
    __syncthreads();

    float s = 0.f;
    #pragma unroll
    for (int q = 0; q < 8; ++q) {
        v[q] = __expf(v[q] - m);
        s += v[q];
    }
    #pragma unroll
    for (int off = 32; off > 0; off >>= 1)
        s += __shfl_down(s, off);
    if (lane == 0) red[wid] = s;
    __syncthreads();
    const float inv = 1.f / (red[0] + red[1] + red[2] + red[3]);

    #pragma unroll
    for (int q = 0; q < 8; ++q)
        row[tid + q * 256] = v[q] * inv;
}

// ---------------------------------------------------------------------------
// PV: out[(b*CH + c)*SEQ + i] = x[same] + sum_j h[b][c][j] * att[i][j]
// NT GEMM: M=c (512), N=i (2048), K=j (2048). Transpose-on-LDS-store for both.
// ---------------------------------------------------------------------------
__global__ __launch_bounds__(256) void pv_kernel(
    const float* __restrict__ h, const float* __restrict__ att,
    const float* __restrict__ x, float* __restrict__ out,
    int b0, long long attStride)
{
    __shared__ float As[16][68];  // [j][c]
    __shared__ float Bs[16][68];  // [j][i]

    const int tid = threadIdx.x;
    const int b = b0 + blockIdx.z;
    const float* attb = att + (size_t)blockIdx.z * attStride;
    const int i0 = blockIdx.x * 64;
    const int c0 = blockIdx.y * 64;
    const int tx = tid & 15;
    const int ty = tid >> 4;

    const float* hb = h + ((size_t)b * CH + c0) * SEQ;

    float acc[4][4] = {};

    for (int j0 = 0; j0 < SEQ; j0 += 16) {
        const int jj = tid & 15;
        const int m0 = tid >> 4;  // 0..15
        #pragma unroll
        for (int q = 0; q < 4; ++q) {
            As[jj][m0 + q * 16] = hb[(size_t)(m0 + q * 16) * SEQ + j0 + jj];
            Bs[jj][m0 + q * 16] = attb[(size_t)(i0 + m0 + q * 16) * SEQ + j0 + jj];
        }
        __syncthreads();
        #pragma unroll
        for (int kk = 0; kk < 16; ++kk) {
            float4 a  = *(const float4*)&As[kk][ty * 4];
            float4 bv = *(const float4*)&Bs[kk][tx * 4];
            float av[4] = {a.x, a.y, a.z, a.w};
            float bw[4] = {bv.x, bv.y, bv.z, bv.w};
            #pragma unroll
            for (int i2 = 0; i2 < 4; ++i2)
                #pragma unroll
                for (int j2 = 0; j2 < 4; ++j2)
                    acc[i2][j2] = fmaf(av[i2], bw[j2], acc[i2][j2]);
        }
        __syncthreads();
    }

    #pragma unroll
    for (int mm = 0; mm < 4; ++mm) {
        const int c = c0 + ty * 4 + mm;
        const size_t base = ((size_t)b * CH + c) * SEQ + i0 + tx * 4;
        float4 xv = *(const float4*)&x[base];
        float4 v;
        v.x = acc[mm][0] + xv.x;
        v.y = acc[mm][1] + xv.y;
        v.z = acc[mm][2] + xv.z;
        v.w = acc[mm][3] + xv.w;
        *(float4*)&out[base] = v;
    }
}

// ---------------------------------------------------------------------------
extern "C" void kernel_launch(void* const* d_in, const int* in_sizes, int n_in,
                              void* d_out, int out_size, void* d_ws, size_t ws_size,
                              hipStream_t stream)
{
    const float* x  = (const float*)d_in[0];
    const float* Wf = (const float*)d_in[1];
    const float* bf = (const float*)d_in[2];
    const float* Wg = (const float*)d_in[3];
    const float* bg = (const float*)d_in[4];
    const float* Wh = (const float*)d_in[5];
    const float* bh = (const float*)d_in[6];
    float* out = (float*)d_out;

    float* ws = (float*)d_ws;
    float* f = ws;                                   // B*CK*SEQ   =  1,048,576 f
    float* g = f + (size_t)BATCH * CKDIM * SEQ;      // B*CK*SEQ
    float* h = g + (size_t)BATCH * CKDIM * SEQ;      // B*CH*SEQ   =  8,388,608 f
    float* att = h + (size_t)BATCH * CH * SEQ;

    const size_t base_floats = 2 * (size_t)BATCH * CKDIM * SEQ + (size_t)BATCH * CH * SEQ;
    const bool multi = ws_size >= (base_floats + (size_t)BATCH * SEQ * SEQ) * sizeof(float);

    // Projections (all batches at once)
    proj_kernel<<<dim3(SEQ / 64, CKDIM / 64, BATCH), 256, 0, stream>>>(Wf, bf, x, f, CKDIM);
    proj_kernel<<<dim3(SEQ / 64, CKDIM / 64, BATCH), 256, 0, stream>>>(Wg, bg, x, g, CKDIM);
    proj_kernel<<<dim3(SEQ / 64, CH / 64, BATCH), 256, 0, stream>>>(Wh, bh, x, h, CH);

    if (multi) {
        const long long s = (long long)SEQ * SEQ;
        scores_kernel<<<dim3(SEQ / 64, SEQ / 64, BATCH), 256, 0, stream>>>(f, g, att, 0, s);
        softmax_kernel<<<dim3(SEQ, 1, BATCH), 256, 0, stream>>>(att, s);
        pv_kernel<<<dim3(SEQ / 64, CH / 64, BATCH), 256, 0, stream>>>(h, att, x, out, 0, s);
    } else {
        // Serialized per-batch (att buffer reused); needs only ~59 MB of ws.
        for (int b = 0; b < BATCH; ++b) {
            scores_kernel<<<dim3(SEQ / 64, SEQ / 64, 1), 256, 0, stream>>>(f, g, att, b, 0);
            softmax_kernel<<<dim3(SEQ, 1, 1), 256, 0, stream>>>(att, 0);
            pv_kernel<<<dim3(SEQ / 64, CH / 64, 1), 256, 0, stream>>>(h, att, x, out, b, 0);
        }
    }
}

// Round 3
// 370.326 us; speedup vs baseline: 2.3246x; 2.3246x over previous
//
#include <hip/hip_runtime.h>
#include <math.h>
#include <stdint.h>

#define BATCH 8
#define CH    512
#define SEQ   2048
#define CKDIM 64

typedef __attribute__((ext_vector_type(8))) short bf16x8;
typedef __attribute__((ext_vector_type(4))) float f32x4;

__device__ __forceinline__ unsigned short f2b(float f) {
    union { float f; uint32_t u; } v; v.f = f;
    uint32_t u = v.u;
    u += 0x7fffu + ((u >> 16) & 1u);   // round-to-nearest-even
    return (unsigned short)(u >> 16);
}
__device__ __forceinline__ float b2f(unsigned short h) {
    union { uint32_t u; float f; } v; v.u = ((uint32_t)h) << 16;
    return v.f;
}

// ---------------------------------------------------------------------------
// x (B, C, L) fp32  ->  xt (B, L, C) bf16   (64x64 LDS-tiled transpose+cast)
// ---------------------------------------------------------------------------
__global__ __launch_bounds__(256) void transpose_cast_kernel(
    const float* __restrict__ x, unsigned short* __restrict__ xt)
{
    __shared__ float t[64][65];
    const int b = blockIdx.z, l0 = blockIdx.x * 64, c0 = blockIdx.y * 64;
    const int tx = threadIdx.x & 63, ty = threadIdx.x >> 6;
    #pragma unroll
    for (int q = 0; q < 16; ++q)
        t[ty + q * 4][tx] = x[((size_t)b * CH + c0 + ty + q * 4) * SEQ + l0 + tx];
    __syncthreads();
    #pragma unroll
    for (int q = 0; q < 16; ++q)
        xt[((size_t)b * SEQ + l0 + ty + q * 4) * CH + c0 + tx] = f2b(t[tx][ty + q * 4]);
}

// ---------------------------------------------------------------------------
// Weight cast: Wfg_b = concat(Wf, Wg) bf16 (128 x 512), Wh_b bf16 (512 x 512),
// bias_fg fp32[128] = concat(bf, bg).
// ---------------------------------------------------------------------------
__global__ __launch_bounds__(256) void castw_kernel(
    const float* __restrict__ Wf, const float* __restrict__ Wg,
    const float* __restrict__ Wh, const float* __restrict__ bf_,
    const float* __restrict__ bg_, unsigned short* __restrict__ Wfgb,
    unsigned short* __restrict__ Whb, float* __restrict__ bias_fg)
{
    const int i = blockIdx.x * 256 + threadIdx.x;
    if (i < 128) bias_fg[i] = (i < 64) ? bf_[i] : bg_[i - 64];
    if (i < 65536) Wfgb[i] = f2b((i < 32768) ? Wf[i] : Wg[i - 32768]);
    if (i < 262144) Whb[i] = f2b(Wh[i]);
}

// ---------------------------------------------------------------------------
// NT bf16 GEMM core: C(128x128) += A(128xK) * B(128xK)^T, rows K-contiguous.
// 256 threads = 4 waves (2x2), each wave 64x64 = 4x4 frags of 16x16x32 MFMA.
// LDS tiles [128 rows][64 bf16] with chunk-XOR swizzle (chunk ^= row&7) so
// fragment ds_read_b128 is conflict-light instead of 8/32-way conflicted.
// Staging: global(16B/lane, coalesced) -> reg -> swizzled ds_write_b128,
// with next-tile loads issued before the MFMA section (latency overlap).
// ---------------------------------------------------------------------------
__device__ __attribute__((always_inline)) inline void gemm_core_nt(
    const unsigned short* __restrict__ A, const int ldA,
    const unsigned short* __restrict__ B, const int ldB,
    const int K,
    unsigned short* __restrict__ ldsA, unsigned short* __restrict__ ldsB,
    f32x4 acc[4][4])
{
    const int tid  = threadIdx.x;
    const int lane = tid & 63;
    const int wm   = tid >> 7;          // wave row (0..1)
    const int wn   = (tid >> 6) & 1;    // wave col (0..1)
    const int fr   = lane & 15;
    const int hi   = lane >> 4;
    const int xo   = lane & 7;

    int goA[4], goB[4], lo[4];
    #pragma unroll
    for (int it = 0; it < 4; ++it) {
        const int idx = tid + it * 256;       // 0..1023 chunk id
        const int row = idx >> 3;             // 0..127
        const int ch  = idx & 7;              // 16B chunk within row
        goA[it] = row * ldA + ch * 8;
        goB[it] = row * ldB + ch * 8;
        lo[it]  = row * 64 + ((ch ^ (row & 7)) * 8);   // swizzled LDS elem off
    }
    int aoff[4], boff[4];
    #pragma unroll
    for (int f = 0; f < 4; ++f) {
        aoff[f] = (wm * 64 + f * 16 + fr) * 64;
        boff[f] = (wn * 64 + f * 16 + fr) * 64;
    }
    const int coff0 = ((0 + hi) ^ xo) * 8;   // kk=0 chunk offset (swizzled)
    const int coff1 = ((4 + hi) ^ xo) * 8;   // kk=1

    uint4 ra[4], rb[4];
    #pragma unroll
    for (int it = 0; it < 4; ++it) {
        ra[it] = *(const uint4*)(A + goA[it]);
        rb[it] = *(const uint4*)(B + goB[it]);
    }

    for (int k0 = 0; k0 < K; k0 += 64) {
        #pragma unroll
        for (int it = 0; it < 4; ++it) {
            *(uint4*)&ldsA[lo[it]] = ra[it];
            *(uint4*)&ldsB[lo[it]] = rb[it];
        }
        __syncthreads();
        if (k0 + 64 < K) {   // issue next-tile loads before MFMA (overlap)
            #pragma unroll
            for (int it = 0; it < 4; ++it) {
                ra[it] = *(const uint4*)(A + goA[it] + k0 + 64);
                rb[it] = *(const uint4*)(B + goB[it] + k0 + 64);
            }
        }
        #pragma unroll
        for (int kk = 0; kk < 2; ++kk) {
            const int co = kk ? coff1 : coff0;
            bf16x8 af[4], bg[4];
            #pragma unroll
            for (int f = 0; f < 4; ++f) {
                af[f] = *(const bf16x8*)&ldsA[aoff[f] + co];
                bg[f] = *(const bf16x8*)&ldsB[boff[f] + co];
            }
            #pragma unroll
            for (int m = 0; m < 4; ++m)
                #pragma unroll
                for (int n = 0; n < 4; ++n)
                    acc[m][n] = __builtin_amdgcn_mfma_f32_16x16x32_bf16(
                        af[m], bg[n], acc[m][n], 0, 0, 0);
        }
        __syncthreads();
    }
}

// bf16 epilogue: acc -> LDS C-tile (128x128 bf16 = 32KB, reuses staging LDS)
// -> coalesced 16B global stores. Optional per-row / per-col fp32 bias.
__device__ __attribute__((always_inline)) inline void epilogue_store_bf16(
    unsigned short* __restrict__ lds, f32x4 acc[4][4],
    unsigned short* __restrict__ outBase, const int ldOut,
    const float* __restrict__ rowBias, const float* __restrict__ colBias)
{
    const int tid = threadIdx.x;
    const int lane = tid & 63;
    const int wm = tid >> 7, wn = (tid >> 6) & 1;
    const int fr = lane & 15, hi = lane >> 4;
    #pragma unroll
    for (int m = 0; m < 4; ++m) {
        const int m0 = wm * 64 + m * 16 + hi * 4;
        #pragma unroll
        for (int n = 0; n < 4; ++n) {
            const int nn = wn * 64 + n * 16 + fr;
            const float cb = colBias ? colBias[nn] : 0.f;
            #pragma unroll
            for (int e = 0; e < 4; ++e) {
                float v = acc[m][n][e] + cb;
                if (rowBias) v += rowBias[m0 + e];
                lds[(m0 + e) * 128 + nn] = f2b(v);
            }
        }
    }
    __syncthreads();
    #pragma unroll
    for (int q = 0; q < 8; ++q) {
        const int idx = tid + q * 256;
        const int row = idx >> 4, ch = idx & 15;
        *(uint4*)&outBase[(size_t)row * ldOut + ch * 8] =
            *(const uint4*)&lds[row * 128 + ch * 8];
    }
}

// ---------------------------------------------------------------------------
// proj_fg: fg_t[b][i][n] = sum_c xt[b][i][c] * Wfg[n][c] + bias_fg[n]
//   (n 0..63 = f, 64..127 = g).  M=SEQ, N=128, K=CH.
// ---------------------------------------------------------------------------
__global__ __launch_bounds__(256) void proj_fg_kernel(
    const unsigned short* __restrict__ xt, const unsigned short* __restrict__ Wfg,
    const float* __restrict__ bias_fg, unsigned short* __restrict__ fg_t)
{
    __shared__ unsigned short lds[16384];
    const int b = blockIdx.z, i0 = blockIdx.x * 128;
    const unsigned short* A = xt + ((size_t)b * SEQ + i0) * CH;
    f32x4 acc[4][4];
    const f32x4 z = {0.f, 0.f, 0.f, 0.f};
    #pragma unroll
    for (int m = 0; m < 4; ++m)
        #pragma unroll
        for (int n = 0; n < 4; ++n) acc[m][n] = z;
    gemm_core_nt(A, CH, Wfg, CH, CH, lds, lds + 8192, acc);
    epilogue_store_bf16(lds, acc, fg_t + ((size_t)b * SEQ + i0) * 128, 128,
                        nullptr, bias_fg);
}

// ---------------------------------------------------------------------------
// proj_h: h_b[b][c][l] = sum_k Wh[c][k] * xt[b][l][k] + bh[c].
//   M=CH(c), N=SEQ(l), K=CH.
// ---------------------------------------------------------------------------
__global__ __launch_bounds__(256) void proj_h_kernel(
    const unsigned short* __restrict__ xt, const unsigned short* __restrict__ Whb,
    const float* __restrict__ bh, unsigned short* __restrict__ h_b)
{
    __shared__ unsigned short lds[16384];
    const int b = blockIdx.z, l0 = blockIdx.x * 128, c0 = blockIdx.y * 128;
    const unsigned short* A = Whb + (size_t)c0 * CH;
    const unsigned short* B = xt + ((size_t)b * SEQ + l0) * CH;
    f32x4 acc[4][4];
    const f32x4 z = {0.f, 0.f, 0.f, 0.f};
    #pragma unroll
    for (int m = 0; m < 4; ++m)
        #pragma unroll
        for (int n = 0; n < 4; ++n) acc[m][n] = z;
    gemm_core_nt(A, CH, B, CH, CH, lds, lds + 8192, acc);
    epilogue_store_bf16(lds, acc,
                        h_b + ((size_t)b * CH + c0) * SEQ + l0, SEQ,
                        bh + c0, nullptr);
}

// ---------------------------------------------------------------------------
// scores: att[b][i][j] = sum_k f_t[i][k] * g_t[j][k]   (K = 64, bf16 out)
// ---------------------------------------------------------------------------
__global__ __launch_bounds__(256) void scores_kernel(
    const unsigned short* __restrict__ fg_t, unsigned short* __restrict__ att,
    int b0, long long attStride)
{
    __shared__ unsigned short lds[16384];
    const int b = b0 + blockIdx.z;
    const int j0 = blockIdx.x * 128, i0 = blockIdx.y * 128;
    const unsigned short* A = fg_t + ((size_t)b * SEQ + i0) * 128;       // f
    const unsigned short* B = fg_t + ((size_t)b * SEQ + j0) * 128 + 64;  // g
    f32x4 acc[4][4];
    const f32x4 z = {0.f, 0.f, 0.f, 0.f};
    #pragma unroll
    for (int m = 0; m < 4; ++m)
        #pragma unroll
        for (int n = 0; n < 4; ++n) acc[m][n] = z;
    gemm_core_nt(A, 128, B, 128, CKDIM, lds, lds + 8192, acc);
    unsigned short* outBase = att + (size_t)blockIdx.z * attStride +
                              (size_t)i0 * SEQ + j0;
    epilogue_store_bf16(lds, acc, outBase, SEQ, nullptr, nullptr);
}

// ---------------------------------------------------------------------------
// Row softmax over j, in place on bf16 att. One wave per row, fp32 math.
// ---------------------------------------------------------------------------
__global__ __launch_bounds__(256) void softmax_kernel(
    unsigned short* __restrict__ att, long long attStride)
{
    const int w = threadIdx.x >> 6, lane = threadIdx.x & 63;
    uint4* rp = (uint4*)(att + (size_t)blockIdx.z * attStride +
                         ((size_t)blockIdx.x * 4 + w) * SEQ);
    uint4 v[4];
    float f[32];
    #pragma unroll
    for (int q = 0; q < 4; ++q) v[q] = rp[lane + q * 64];
    #pragma unroll
    for (int q = 0; q < 4; ++q) {
        const uint32_t w0 = v[q].x, w1 = v[q].y, w2 = v[q].z, w3 = v[q].w;
        f[q * 8 + 0] = b2f((unsigned short)(w0 & 0xffff));
        f[q * 8 + 1] = b2f((unsigned short)(w0 >> 16));
        f[q * 8 + 2] = b2f((unsigned short)(w1 & 0xffff));
        f[q * 8 + 3] = b2f((unsigned short)(w1 >> 16));
        f[q * 8 + 4] = b2f((unsigned short)(w2 & 0xffff));
        f[q * 8 + 5] = b2f((unsigned short)(w2 >> 16));
        f[q * 8 + 6] = b2f((unsigned short)(w3 & 0xffff));
        f[q * 8 + 7] = b2f((unsigned short)(w3 >> 16));
    }
    float mx = -INFINITY;
    #pragma unroll
    for (int q = 0; q < 32; ++q) mx = fmaxf(mx, f[q]);
    #pragma unroll
    for (int off = 32; off > 0; off >>= 1)
        mx = fmaxf(mx, __shfl_xor(mx, off));
    float s = 0.f;
    #pragma unroll
    for (int q = 0; q < 32; ++q) { f[q] = __expf(f[q] - mx); s += f[q]; }
    #pragma unroll
    for (int off = 32; off > 0; off >>= 1)
        s += __shfl_xor(s, off);
    const float inv = 1.f / s;
    #pragma unroll
    for (int q = 0; q < 4; ++q) {
        uint4 o;
        o.x = (uint32_t)f2b(f[q * 8 + 0] * inv) | ((uint32_t)f2b(f[q * 8 + 1] * inv) << 16);
        o.y = (uint32_t)f2b(f[q * 8 + 2] * inv) | ((uint32_t)f2b(f[q * 8 + 3] * inv) << 16);
        o.z = (uint32_t)f2b(f[q * 8 + 4] * inv) | ((uint32_t)f2b(f[q * 8 + 5] * inv) << 16);
        o.w = (uint32_t)f2b(f[q * 8 + 6] * inv) | ((uint32_t)f2b(f[q * 8 + 7] * inv) << 16);
        rp[lane + q * 64] = o;
    }
}

// ---------------------------------------------------------------------------
// pv: out[b][c][i] = x[b][c][i] + sum_j h_b[b][c][j] * att[b][i][j]
//   M=CH(c), N=SEQ(i), K=SEQ(j). fp32 residual epilogue.
// ---------------------------------------------------------------------------
__global__ __launch_bounds__(256) void pv_kernel(
    const unsigned short* __restrict__ h_b, const unsigned short* __restrict__ att,
    const float* __restrict__ x, float* __restrict__ out,
    int b0, long long attStride)
{
    __shared__ unsigned short lds[16384];
    const int b = b0 + blockIdx.z;
    const int i0 = blockIdx.x * 128, c0 = blockIdx.y * 128;
    const unsigned short* A = h_b + ((size_t)b * CH + c0) * SEQ;
    const unsigned short* B = att + (size_t)blockIdx.z * attStride + (size_t)i0 * SEQ;
    f32x4 acc[4][4];
    const f32x4 z = {0.f, 0.f, 0.f, 0.f};
    #pragma unroll
    for (int m = 0; m < 4; ++m)
        #pragma unroll
        for (int n = 0; n < 4; ++n) acc[m][n] = z;
    gemm_core_nt(A, SEQ, B, SEQ, SEQ, lds, lds + 8192, acc);

    const int lane = threadIdx.x & 63;
    const int wm = threadIdx.x >> 7, wn = (threadIdx.x >> 6) & 1;
    const int fr = lane & 15, hi = lane >> 4;
    #pragma unroll
    for (int m = 0; m < 4; ++m)
        #pragma unroll
        for (int n = 0; n < 4; ++n) {
            const int i = i0 + wn * 64 + n * 16 + fr;
            #pragma unroll
            for (int e = 0; e < 4; ++e) {
                const int c = c0 + wm * 64 + m * 16 + hi * 4 + e;
                const size_t o = ((size_t)b * CH + c) * SEQ + i;
                out[o] = acc[m][n][e] + x[o];
            }
        }
}

// ---------------------------------------------------------------------------
extern "C" void kernel_launch(void* const* d_in, const int* in_sizes, int n_in,
                              void* d_out, int out_size, void* d_ws, size_t ws_size,
                              hipStream_t stream)
{
    const float* x  = (const float*)d_in[0];
    const float* Wf = (const float*)d_in[1];
    const float* bf_ = (const float*)d_in[2];
    const float* Wg = (const float*)d_in[3];
    const float* bg_ = (const float*)d_in[4];
    const float* Wh = (const float*)d_in[5];
    const float* bh = (const float*)d_in[6];
    float* out = (float*)d_out;

    unsigned short* ws = (unsigned short*)d_ws;
    size_t off = 0;
    unsigned short* xt   = ws + off; off += (size_t)BATCH * SEQ * CH;   // 8,388,608
    unsigned short* Wfgb = ws + off; off += 128 * CH;                   // 65,536
    unsigned short* Whb  = ws + off; off += CH * CH;                    // 262,144
    unsigned short* fg_t = ws + off; off += (size_t)BATCH * SEQ * 128;  // 2,097,152
    unsigned short* h_b  = ws + off; off += (size_t)BATCH * CH * SEQ;   // 8,388,608
    float* bias_fg = (float*)(ws + off); off += 256;                    // 128 fp32
    unsigned short* att  = ws + off;

    const size_t need_multi = (off + (size_t)BATCH * SEQ * SEQ) * sizeof(unsigned short);
    const bool multi = ws_size >= need_multi;

    transpose_cast_kernel<<<dim3(SEQ / 64, CH / 64, BATCH), 256, 0, stream>>>(x, xt);
    castw_kernel<<<dim3(1024), 256, 0, stream>>>(Wf, Wg, Wh, bf_, bg_, Wfgb, Whb, bias_fg);
    proj_fg_kernel<<<dim3(SEQ / 128, 1, BATCH), 256, 0, stream>>>(xt, Wfgb, bias_fg, fg_t);
    proj_h_kernel<<<dim3(SEQ / 128, CH / 128, BATCH), 256, 0, stream>>>(xt, Whb, bh, h_b);

    if (multi) {
        const long long s = (long long)SEQ * SEQ;
        scores_kernel<<<dim3(SEQ / 128, SEQ / 128, BATCH), 256, 0, stream>>>(fg_t, att, 0, s);
        softmax_kernel<<<dim3(SEQ / 4, 1, BATCH), 256, 0, stream>>>(att, s);
        pv_kernel<<<dim3(SEQ / 128, CH / 128, BATCH), 256, 0, stream>>>(h_b, att, x, out, 0, s);
    } else {
        for (int b = 0; b < BATCH; ++b) {
            scores_kernel<<<dim3(SEQ / 128, SEQ / 128, 1), 256, 0, stream>>>(fg_t, att, b, 0);
            softmax_kernel<<<dim3(SEQ / 4, 1, 1), 256, 0, stream>>>(att, 0);
            pv_kernel<<<dim3(SEQ / 128, CH / 128, 1), 256, 0, stream>>>(h_b, att, x, out, b, 0);
        }
    }
}